// Round 5
// baseline (7412.185 us; speedup 1.0000x reference)
//
#include <hip/hip_runtime.h>
#include <hip/hip_bf16.h>

typedef __bf16 bf16;
typedef bf16 bf16x8 __attribute__((ext_vector_type(8)));
typedef float f32x4 __attribute__((ext_vector_type(4)));
typedef unsigned int u32;
typedef u32 u32x4 __attribute__((ext_vector_type(4)));

#define AGENT __HIP_MEMORY_SCOPE_AGENT

// ---- problem sizes ----
#define TT 512
#define BB 64
#define HH 512
#define TB (TT*BB)      // 32768 rows
#define G3 (3*HH)       // 1536 gates per dir

// ---- workspace layout (bytes) ----
#define GI_OFF   0L
#define GI_BYTES (2L*TB*G3*2)          // bf16 gi, both dirs
#define L0_OFF   (GI_OFF + GI_BYTES)
#define L0_BYTES (1L*TB*1024*2)        // bf16 layer-0 output
#define XB_OFF   (L0_OFF + L0_BYTES)
#define XB_BYTES (1L*TB*512*2)         // bf16 x
#define W0_OFF   (XB_OFF + XB_BYTES)
#define W0_BYTES (3072L*512*2)         // packed w_ih L0 (f then b)
#define W1_OFF   (W0_OFF + W0_BYTES)
#define W1_BYTES (3072L*1024*2)        // packed w_ih L1
#define HB_OFF   (W1_OFF + W1_BYTES)
#define HB_BYTES (2L*2*64*256*4)       // h exchange: [phase][dir][64][256] u32 (bf16 pairs)
#define FL_OFF   (HB_OFF + HB_BYTES)
#define FL_BYTES 1024                  // (unused; kept for ws sizing stability)
#define WS_NEED  (FL_OFF + FL_BYTES)

// ============================ helpers ============================
__device__ __forceinline__ float sigm(float x) {
    return __builtin_amdgcn_rcpf(1.0f + __expf(-x));
}
__device__ __forceinline__ float tanh_f(float x) {
    return 1.0f - 2.0f * __builtin_amdgcn_rcpf(1.0f + __expf(2.0f * x));
}

// ============================ kernels ============================
__global__ void sentinel(float* o) { o[0] = 1.0e9f; }  // ws too small marker

__global__ void cvt_f32_bf16(const float* __restrict__ s, bf16* __restrict__ d, long n) {
    long i = (long)blockIdx.x * blockDim.x + threadIdx.x;
    long st = (long)gridDim.x * blockDim.x;
    for (; i < n; i += st) d[i] = (bf16)s[i];
}

// C[m, n] = sum_k A[m,k] * Bw[n,k]; A row-major [32768,K] bf16, Bw [3072,K] bf16.
// Output written as bf16 into gi[dir][m][col], dir = n>=1536.
__global__ __launch_bounds__(256, 2)
void gemm_gi(const bf16* __restrict__ A, const bf16* __restrict__ Bw,
             bf16* __restrict__ gi, int K)
{
    __shared__ bf16 aS[128*72];
    __shared__ bf16 bS[128*72];
    const int tid = threadIdx.x;
    const int mt = blockIdx.x & 255;
    const int nt = blockIdx.x >> 8;
    const long m0 = (long)mt * 128;
    const int n0 = nt * 128;
    const int wave = tid >> 6, lane = tid & 63;
    const int q = lane >> 4, lr = lane & 15;
    const int wm = wave & 1, wn = wave >> 1;
    f32x4 acc[4][4] = {};

    for (int kb = 0; kb < K; kb += 64) {
        __syncthreads();
        #pragma unroll
        for (int p = 0; p < 4; ++p) {
            int idx = tid + p * 256;
            int row = idx >> 3, qd = idx & 7;
            *(uint4*)(aS + row*72 + qd*8) = *(const uint4*)(A + (m0+row)*K + kb + qd*8);
            *(uint4*)(bS + row*72 + qd*8) = *(const uint4*)(Bw + (long)(n0+row)*K + kb + qd*8);
        }
        __syncthreads();
        #pragma unroll
        for (int kk = 0; kk < 2; ++kk) {
            bf16x8 af[4], bfr[4];
            #pragma unroll
            for (int sm = 0; sm < 4; ++sm)
                af[sm] = *(const bf16x8*)(aS + (wm*64 + sm*16 + lr)*72 + kk*32 + q*8);
            #pragma unroll
            for (int sn = 0; sn < 4; ++sn)
                bfr[sn] = *(const bf16x8*)(bS + (wn*64 + sn*16 + lr)*72 + kk*32 + q*8);
            #pragma unroll
            for (int sm = 0; sm < 4; ++sm)
                #pragma unroll
                for (int sn = 0; sn < 4; ++sn)
                    acc[sm][sn] = __builtin_amdgcn_mfma_f32_16x16x32_bf16(
                        af[sm], bfr[sn], acc[sm][sn], 0, 0, 0);
        }
    }
    #pragma unroll
    for (int sm = 0; sm < 4; ++sm) {
        #pragma unroll
        for (int sn = 0; sn < 4; ++sn) {
            int n_g = n0 + wn*64 + sn*16 + lr;
            int d = (n_g >= G3) ? 1 : 0;
            int cg = n_g - d * G3;
            u32* gout = (u32*)(gi + (long)d * TB * G3);
            #pragma unroll
            for (int i = 0; i < 4; ++i) {
                long m_g = m0 + wm*64 + sm*16 + q*4 + i;
                unsigned short hs = __builtin_bit_cast(unsigned short, (bf16)acc[sm][sn][i]);
                int other = __shfl_xor((int)hs, 1, 64);
                if (!(lr & 1))
                    gout[(m_g * G3 + cg) >> 1] = (u32)hs | (((u32)(unsigned short)other) << 16);
            }
        }
    }
}

// Persistent recurrence: 64 blocks (2 dirs x 32 h-slices of 16 cols), 256 thr.
//
// Round-5 change: OVERLAPPED BULK INGEST + CHUNK-GRANULAR RETRY.
// R4 evidence: only ~1.5-2 poll rounds/step but each bulk 16KB/wave sc0sc1
// round costs ~4-5k cycles under 8-10MB/step coherent-path congestion. Now:
// (a) the 16 bulk loads for step s+1 are ISSUED right after publishing
//     h(s+1) -- they fly overlapped with y-write + gi prefetch + peers'
//     publish window; at the next loop top we only wait + validate.
// (b) validation is per 16B chunk -> per-lane 16-bit miss mask; the retry
//     loop re-loads ONLY missing chunks (a straggler slice dirties one
//     chunk for half the lanes ~ 0.5KB/wave vs 16KB) -- retries are cheap
//     in both latency and coherent-path traffic.
// Rule-18 guard: sched_barrier(0) after each split s_waitcnt so validation/
// MFMAs cannot hoist above the wait.
//
// Sync protocol (unchanged): SELF-VALIDATING DATA. GRU => |h|<1<2 => bit14
// of every published bf16 is 0. tag(d)=(d>>1)&1 for generation d in phase
// buffer d&1; tag(d)!=tag(d-2) and tag(s+1)!=tag(s-1), so the early bulk
// issue can never accept the previous occupant. Producer ORs the tag into
// each packed u32, stores fire-and-forget (relaxed agent). Consumer
// validates per-u32 within each chunk; torn mixes caught. Tag bits STRIPPED
// (AND 0xBFFFBFFF) before MFMAs (bit14 = x2^128). Deadlock-free by induction
// from pre-loop publish(0); ABA-free (gen d+2 requires all consumed d+1).
__global__ __launch_bounds__(256, 1)
void gru_rec(const bf16* __restrict__ gi,
             const float* __restrict__ whh_f, const float* __restrict__ whh_b,
             const float* __restrict__ bih_f, const float* __restrict__ bhh_f,
             const float* __restrict__ bih_b, const float* __restrict__ bhh_b,
             const float* __restrict__ h0,
             u32* hbuf,
             void* out, float* hn_out, int layer, int out_f32)
{
    __shared__ bf16 wS[48*512];   // XOR-swizzled: chunk c stored at c^(row&7)
    const int tid = threadIdx.x;
    const int dir = blockIdx.x & 1;
    const int slice = blockIdx.x >> 1;       // 0..31
    const int wave = tid >> 6, lane = tid & 63;
    const int q = lane >> 4, lr = lane & 15;

    const float* whh = dir ? whh_b : whh_f;
    const float* bih = dir ? bih_b : bih_f;
    const float* bhh = dir ? bhh_b : bhh_f;

    // stage W_hh slice -> LDS bf16, 16B chunks, XOR bank swizzle
    for (int idx = tid; idx < 48*64; idx += 256) {
        int row = idx >> 6, c = idx & 63;
        int g = row >> 4, cc = row & 15;
        const float* src = whh + (size_t)(g*HH + slice*16 + cc)*HH + c*8;
        bf16x8 v;
        #pragma unroll
        for (int j = 0; j < 8; ++j) v[j] = (bf16)src[j];
        *(bf16x8*)(wS + row*512 + ((c ^ (row & 7)) << 3)) = v;
    }
    __syncthreads();

    const int sw = lr & 7;

    // ---- hoist W fragments LDS -> registers, ONCE (48 x bf16x8 = 192 VGPR).
    bf16x8 wf[3][16];
    #pragma unroll
    for (int g = 0; g < 3; ++g)
        #pragma unroll
        for (int KK = 0; KK < 16; ++KK)
            wf[g][KK] = *(const bf16x8*)(wS + (g*16 + lr)*512 + (((KK*4 + q) ^ sw) << 3));

    const int col = slice*16 + lr;
    const float bi0 = bih[col], bi1 = bih[HH+col], bi2 = bih[2*HH+col];
    const float bh0 = bhh[col], bh1 = bhh[HH+col], bh2 = bhh[2*HH+col];
    const int mrow = wave*16 + q*4;

    float hprev[4];
    #pragma unroll
    for (int i = 0; i < 4; ++i)
        hprev[i] = h0[((2*layer + dir)*BB + mrow + i)*HH + col];

    // publish hv[] into phase buffer ph with tag pattern pat (fire-and-forget)
    auto publish = [&](int ph, u32 pat, const float* hv) {
        u32* hb = hbuf + (((ph << 1) | dir) * 64) * 256;
        #pragma unroll
        for (int i = 0; i < 4; ++i) {
            unsigned short hs = __builtin_bit_cast(unsigned short, (bf16)hv[i]);
            int other = __shfl_xor((int)hs, 1, 64);
            if (!(lr & 1)) {
                u32 u = ((u32)hs | (((u32)(unsigned short)other) << 16)) | pat;
                __hip_atomic_store(hb + (mrow + i)*256 + (col >> 1), u,
                                   __ATOMIC_RELAXED, AGENT);
            }
        }
    };

    // ingest registers (live across iterations: issued at end of step s-1,
    // consumed at top of step s)
    u32x4 a0,a1,a2,a3,a4,a5,a6,a7,a8,a9,a10,a11,a12,a13,a14,a15;

#define ISSUE_ALL(HRP) \
    asm volatile( \
        "global_load_dwordx4 %0, %16, off sc0 sc1\n\t" \
        "global_load_dwordx4 %1, %16, off offset:64 sc0 sc1\n\t" \
        "global_load_dwordx4 %2, %16, off offset:128 sc0 sc1\n\t" \
        "global_load_dwordx4 %3, %16, off offset:192 sc0 sc1\n\t" \
        "global_load_dwordx4 %4, %16, off offset:256 sc0 sc1\n\t" \
        "global_load_dwordx4 %5, %16, off offset:320 sc0 sc1\n\t" \
        "global_load_dwordx4 %6, %16, off offset:384 sc0 sc1\n\t" \
        "global_load_dwordx4 %7, %16, off offset:448 sc0 sc1\n\t" \
        "global_load_dwordx4 %8, %16, off offset:512 sc0 sc1\n\t" \
        "global_load_dwordx4 %9, %16, off offset:576 sc0 sc1\n\t" \
        "global_load_dwordx4 %10, %16, off offset:640 sc0 sc1\n\t" \
        "global_load_dwordx4 %11, %16, off offset:704 sc0 sc1\n\t" \
        "global_load_dwordx4 %12, %16, off offset:768 sc0 sc1\n\t" \
        "global_load_dwordx4 %13, %16, off offset:832 sc0 sc1\n\t" \
        "global_load_dwordx4 %14, %16, off offset:896 sc0 sc1\n\t" \
        "global_load_dwordx4 %15, %16, off offset:960 sc0 sc1" \
        : "=&v"(a0),"=&v"(a1),"=&v"(a2),"=&v"(a3), \
          "=&v"(a4),"=&v"(a5),"=&v"(a6),"=&v"(a7), \
          "=&v"(a8),"=&v"(a9),"=&v"(a10),"=&v"(a11), \
          "=&v"(a12),"=&v"(a13),"=&v"(a14),"=&v"(a15) \
        : "v"(HRP) \
        : "memory")

// validate chunk AC; set bit BIT in MV if invalid (per-lane)
#define CHK1(AC, BIT, MV) { \
        u32 bnd_ = AC[0] & AC[1] & AC[2] & AC[3]; \
        u32 brd_ = AC[0] | AC[1] | AC[2] | AC[3]; \
        bool bad_ = pat ? ((bnd_ & 0x40004000u) != 0x40004000u) \
                        : ((brd_ & 0x40004000u) != 0u); \
        MV |= bad_ ? (1u << BIT) : 0u; }
#define CHKALL(MV) \
        CHK1(a0,0,MV)  CHK1(a1,1,MV)   CHK1(a2,2,MV)   CHK1(a3,3,MV) \
        CHK1(a4,4,MV)  CHK1(a5,5,MV)   CHK1(a6,6,MV)   CHK1(a7,7,MV) \
        CHK1(a8,8,MV)  CHK1(a9,9,MV)   CHK1(a10,10,MV) CHK1(a11,11,MV) \
        CHK1(a12,12,MV) CHK1(a13,13,MV) CHK1(a14,14,MV) CHK1(a15,15,MV)

// predicated re-load of one missing chunk (exec-masked; skipped if no lane)
#define RETRY1(BIT, AC, OFFA) \
        if (miss & (1u << BIT)) { \
            asm volatile("global_load_dwordx4 %0, %1, off " OFFA " sc0 sc1" \
                         : "=&v"(AC) : "v"(hr) : "memory"); }

    // initial h publish: gen d=0, phase 0, tag 0; then early bulk issue for s=0
    publish(0, 0u, hprev);
    {
        const u32* hr0 = hbuf + ((0 | dir)*64 + wave*16 + lr)*256 + q*4;
        ISSUE_ALL(hr0);
    }

    const bf16* gbase = gi + (long)dir * TB * G3;
    bf16 gp[3][4];
    {
        int t0 = dir ? (TT-1) : 0;
        #pragma unroll
        for (int g = 0; g < 3; ++g)
            #pragma unroll
            for (int i = 0; i < 4; ++i)
                gp[g][i] = gbase[(long)(t0*BB + mrow + i)*G3 + g*HH + col];
    }

    for (int s = 0; s < TT; ++s) {
        const int t = dir ? (TT-1-s) : s;
        const u32 pat = (s & 2) ? 0x40004000u : 0u;   // tag(d=s) = (s>>1)&1
        const u32* hr = hbuf + ((((s & 1) << 1) | dir)*64 + wave*16 + lr)*256 + q*4;

        // ---- finish the overlapped bulk ingest, then chunk-granular retry
        asm volatile("s_waitcnt vmcnt(0)" ::: "memory");
        __builtin_amdgcn_sched_barrier(0);
        u32 miss = 0u;
        CHKALL(miss);
        while (__any((int)(miss != 0u))) {
            RETRY1(0,a0,"")              RETRY1(1,a1,"offset:64")
            RETRY1(2,a2,"offset:128")    RETRY1(3,a3,"offset:192")
            RETRY1(4,a4,"offset:256")    RETRY1(5,a5,"offset:320")
            RETRY1(6,a6,"offset:384")    RETRY1(7,a7,"offset:448")
            RETRY1(8,a8,"offset:512")    RETRY1(9,a9,"offset:576")
            RETRY1(10,a10,"offset:640")  RETRY1(11,a11,"offset:704")
            RETRY1(12,a12,"offset:768")  RETRY1(13,a13,"offset:832")
            RETRY1(14,a14,"offset:896")  RETRY1(15,a15,"offset:960")
            asm volatile("s_waitcnt vmcnt(0)" ::: "memory");
            __builtin_amdgcn_sched_barrier(0);
            u32 m2 = 0u;
            CHKALL(m2);
            miss = m2;
        }
        // ---- strip tag bits (bit14 == x2^128 -- must NOT reach the MFMAs).
        if (pat) {
            const u32 SM = 0xBFFFBFFFu;
            auto strip = [&](u32x4& v) {
                v[0] &= SM; v[1] &= SM; v[2] &= SM; v[3] &= SM;
            };
            strip(a0);  strip(a1);  strip(a2);  strip(a3);
            strip(a4);  strip(a5);  strip(a6);  strip(a7);
            strip(a8);  strip(a9);  strip(a10); strip(a11);
            strip(a12); strip(a13); strip(a14); strip(a15);
        }
        // ---- 48 MFMAs, register-only (gh = h @ W_slice^T)
        f32x4 acc0 = {0,0,0,0}, acc1 = {0,0,0,0}, acc2 = {0,0,0,0};
#define KSTEP(KK, AU) { \
            bf16x8 av = __builtin_bit_cast(bf16x8, AU); \
            acc0 = __builtin_amdgcn_mfma_f32_16x16x32_bf16(av, wf[0][KK], acc0, 0,0,0); \
            acc1 = __builtin_amdgcn_mfma_f32_16x16x32_bf16(av, wf[1][KK], acc1, 0,0,0); \
            acc2 = __builtin_amdgcn_mfma_f32_16x16x32_bf16(av, wf[2][KK], acc2, 0,0,0); }
        KSTEP(0,a0)  KSTEP(1,a1)  KSTEP(2,a2)  KSTEP(3,a3)
        KSTEP(4,a4)  KSTEP(5,a5)  KSTEP(6,a6)  KSTEP(7,a7)
        KSTEP(8,a8)  KSTEP(9,a9)  KSTEP(10,a10) KSTEP(11,a11)
        KSTEP(12,a12) KSTEP(13,a13) KSTEP(14,a14) KSTEP(15,a15)
#undef KSTEP
        // ---- fused gates (fp32)
        float hnew[4];
        #pragma unroll
        for (int i = 0; i < 4; ++i) {
            float r = sigm((float)gp[0][i] + bi0 + acc0[i] + bh0);
            float z = sigm((float)gp[1][i] + bi1 + acc1[i] + bh1);
            float n = tanh_f((float)gp[2][i] + bi2 + r * (acc2[i] + bh2));
            float h = (1.0f - z) * n + z * hprev[i];
            hprev[i] = h;
            hnew[i] = h;
        }
        // ---- publish h_new immediately, then EARLY-ISSUE next bulk ingest
        if (s < TT-1) {
            u32 npat = ((s+1) & 2) ? 0x40004000u : 0u;  // tag(d=s+1)
            publish((s+1) & 1, npat, hnew);
            const u32* hrn = hbuf + (((((s+1) & 1) << 1) | dir)*64 + wave*16 + lr)*256 + q*4;
            ISSUE_ALL(hrn);
        }
        // ---- write y[t] (overlaps with in-flight bulk loads)
        if (out_f32) {
            float* yo = (float*)out;
            #pragma unroll
            for (int i = 0; i < 4; ++i)
                yo[(long)(t*BB + mrow + i)*1024 + dir*HH + col] = hnew[i];
        } else {
            bf16* yo = (bf16*)out;
            #pragma unroll
            for (int i = 0; i < 4; ++i)
                yo[(long)(t*BB + mrow + i)*1024 + dir*HH + col] = (bf16)hnew[i];
        }
        if (s == TT-1) {
            #pragma unroll
            for (int i = 0; i < 4; ++i)
                hn_out[((2*layer + dir)*BB + mrow + i)*HH + col] = hnew[i];
            break;
        }
        // ---- prefetch next gi (overlaps with in-flight bulk loads)
        int tn = dir ? (TT-2-s) : (s+1);
        #pragma unroll
        for (int g = 0; g < 3; ++g)
            #pragma unroll
            for (int i = 0; i < 4; ++i)
                gp[g][i] = gbase[(long)(tn*BB + mrow + i)*G3 + g*HH + col];
    }
#undef ISSUE_ALL
#undef CHK1
#undef CHKALL
#undef RETRY1
}

// ============================ launch ============================
extern "C" void kernel_launch(void* const* d_in, const int* in_sizes, int n_in,
                              void* d_out, int out_size, void* d_ws, size_t ws_size,
                              hipStream_t stream)
{
    const float* x     = (const float*)d_in[0];
    const float* h0    = (const float*)d_in[1];
    const float* wih0f = (const float*)d_in[2];
    const float* whh0f = (const float*)d_in[3];
    const float* bih0f = (const float*)d_in[4];
    const float* bhh0f = (const float*)d_in[5];
    const float* wih0b = (const float*)d_in[6];
    const float* whh0b = (const float*)d_in[7];
    const float* bih0b = (const float*)d_in[8];
    const float* bhh0b = (const float*)d_in[9];
    const float* wih1f = (const float*)d_in[10];
    const float* whh1f = (const float*)d_in[11];
    const float* bih1f = (const float*)d_in[12];
    const float* bhh1f = (const float*)d_in[13];
    const float* wih1b = (const float*)d_in[14];
    const float* whh1b = (const float*)d_in[15];
    const float* bih1b = (const float*)d_in[16];
    const float* bhh1b = (const float*)d_in[17];

    if (ws_size < (size_t)WS_NEED) {
        sentinel<<<1, 1, 0, stream>>>((float*)d_out);
        return;
    }
    char* ws = (char*)d_ws;
    bf16* gi    = (bf16*)(ws + GI_OFF);
    bf16* l0out = (bf16*)(ws + L0_OFF);
    bf16* xb    = (bf16*)(ws + XB_OFF);
    bf16* w0    = (bf16*)(ws + W0_OFF);
    bf16* w1    = (bf16*)(ws + W1_OFF);
    u32*  hbuf  = (u32*)(ws + HB_OFF);
    float* hn   = (float*)d_out + (long)TB * 1024;

    // 0xFF = tag-bit-1 everywhere: cold/stale buffers mismatch the first
    // expected generations (d=0,1 have tag 0), so polls wait for real data.
    // Between layers no re-memset is needed: layer 0 ends with gens 510/511
    // (both tag 1) resident, and layer 1 starts expecting tag 0.
    hipMemsetAsync(hbuf, 0xFF, HB_BYTES, stream);

    // bf16 packing
    cvt_f32_bf16<<<2048, 256, 0, stream>>>(x, xb, (long)TB * 512);
    cvt_f32_bf16<<<256, 256, 0, stream>>>(wih0f, w0,             (long)G3 * 512);
    cvt_f32_bf16<<<256, 256, 0, stream>>>(wih0b, w0 + G3*512L,   (long)G3 * 512);
    cvt_f32_bf16<<<256, 256, 0, stream>>>(wih1f, w1,             (long)G3 * 1024);
    cvt_f32_bf16<<<256, 256, 0, stream>>>(wih1b, w1 + G3*1024L,  (long)G3 * 1024);

    // layer 0
    gemm_gi<<<dim3(256 * 24), 256, 0, stream>>>(xb, w0, gi, 512);
    gru_rec<<<64, 256, 0, stream>>>(gi, whh0f, whh0b, bih0f, bhh0f, bih0b, bhh0b,
                                    h0, hbuf, (void*)l0out, hn, 0, 0);
    // layer 1
    gemm_gi<<<dim3(256 * 24), 256, 0, stream>>>(l0out, w1, gi, 1024);
    gru_rec<<<64, 256, 0, stream>>>(gi, whh1f, whh1b, bih1f, bhh1f, bih1b, bhh1b,
                                    h0, hbuf, d_out, hn, 1, 1);
}

// Round 7
// 4410.125 us; speedup vs baseline: 1.6807x; 1.6807x over previous
//
#include <hip/hip_runtime.h>
#include <hip/hip_bf16.h>

typedef __bf16 bf16;
typedef bf16 bf16x8 __attribute__((ext_vector_type(8)));
typedef float f32x4 __attribute__((ext_vector_type(4)));
typedef unsigned int u32;
typedef u32 u32x4 __attribute__((ext_vector_type(4)));

#define AGENT __HIP_MEMORY_SCOPE_AGENT

// ---- problem sizes ----
#define TT 512
#define BB 64
#define HH 512
#define TB (TT*BB)      // 32768 rows
#define G3 (3*HH)       // 1536 gates per dir

// ---- workspace layout (bytes) ----
#define GI_OFF   0L
#define GI_BYTES (2L*TB*G3*2)          // bf16 gi, both dirs
#define L0_OFF   (GI_OFF + GI_BYTES)
#define L0_BYTES (1L*TB*1024*2)        // bf16 layer-0 output
#define XB_OFF   (L0_OFF + L0_BYTES)
#define XB_BYTES (1L*TB*512*2)         // bf16 x
#define W0_OFF   (XB_OFF + XB_BYTES)
#define W0_BYTES (3072L*512*2)         // packed w_ih L0 (f then b)
#define W1_OFF   (W0_OFF + W0_BYTES)
#define W1_BYTES (3072L*1024*2)        // packed w_ih L1
#define HB_OFF   (W1_OFF + W1_BYTES)
#define HB_BYTES (2L*2*64*256*4)       // h exchange: [phase][dir][64][256] u32 (bf16 pairs)
#define FL_OFF   (HB_OFF + HB_BYTES)
#define FL_BYTES 1024                  // flags[dir][wave][32 slices] u32
#define WS_NEED  (FL_OFF + FL_BYTES)

// ============================ helpers ============================
__device__ __forceinline__ float sigm(float x) {
    return __builtin_amdgcn_rcpf(1.0f + __expf(-x));
}
__device__ __forceinline__ float tanh_f(float x) {
    return 1.0f - 2.0f * __builtin_amdgcn_rcpf(1.0f + __expf(2.0f * x));
}

// ============================ kernels ============================
__global__ void sentinel(float* o) { o[0] = 1.0e9f; }  // ws too small marker

__global__ void cvt_f32_bf16(const float* __restrict__ s, bf16* __restrict__ d, long n) {
    long i = (long)blockIdx.x * blockDim.x + threadIdx.x;
    long st = (long)gridDim.x * blockDim.x;
    for (; i < n; i += st) d[i] = (bf16)s[i];
}

// C[m, n] = sum_k A[m,k] * Bw[n,k]; A row-major [32768,K] bf16, Bw [3072,K] bf16.
// Output written as bf16 into gi[dir][m][col], dir = n>=1536.
__global__ __launch_bounds__(256, 2)
void gemm_gi(const bf16* __restrict__ A, const bf16* __restrict__ Bw,
             bf16* __restrict__ gi, int K)
{
    __shared__ bf16 aS[128*72];
    __shared__ bf16 bS[128*72];
    const int tid = threadIdx.x;
    const int mt = blockIdx.x & 255;
    const int nt = blockIdx.x >> 8;
    const long m0 = (long)mt * 128;
    const int n0 = nt * 128;
    const int wave = tid >> 6, lane = tid & 63;
    const int q = lane >> 4, lr = lane & 15;
    const int wm = wave & 1, wn = wave >> 1;
    f32x4 acc[4][4] = {};

    for (int kb = 0; kb < K; kb += 64) {
        __syncthreads();
        #pragma unroll
        for (int p = 0; p < 4; ++p) {
            int idx = tid + p * 256;
            int row = idx >> 3, qd = idx & 7;
            *(uint4*)(aS + row*72 + qd*8) = *(const uint4*)(A + (m0+row)*K + kb + qd*8);
            *(uint4*)(bS + row*72 + qd*8) = *(const uint4*)(Bw + (long)(n0+row)*K + kb + qd*8);
        }
        __syncthreads();
        #pragma unroll
        for (int kk = 0; kk < 2; ++kk) {
            bf16x8 af[4], bfr[4];
            #pragma unroll
            for (int sm = 0; sm < 4; ++sm)
                af[sm] = *(const bf16x8*)(aS + (wm*64 + sm*16 + lr)*72 + kk*32 + q*8);
            #pragma unroll
            for (int sn = 0; sn < 4; ++sn)
                bfr[sn] = *(const bf16x8*)(bS + (wn*64 + sn*16 + lr)*72 + kk*32 + q*8);
            #pragma unroll
            for (int sm = 0; sm < 4; ++sm)
                #pragma unroll
                for (int sn = 0; sn < 4; ++sn)
                    acc[sm][sn] = __builtin_amdgcn_mfma_f32_16x16x32_bf16(
                        af[sm], bfr[sn], acc[sm][sn], 0, 0, 0);
        }
    }
    #pragma unroll
    for (int sm = 0; sm < 4; ++sm) {
        #pragma unroll
        for (int sn = 0; sn < 4; ++sn) {
            int n_g = n0 + wn*64 + sn*16 + lr;
            int d = (n_g >= G3) ? 1 : 0;
            int cg = n_g - d * G3;
            u32* gout = (u32*)(gi + (long)d * TB * G3);
            #pragma unroll
            for (int i = 0; i < 4; ++i) {
                long m_g = m0 + wm*64 + sm*16 + q*4 + i;
                unsigned short hs = __builtin_bit_cast(unsigned short, (bf16)acc[sm][sn][i]);
                int other = __shfl_xor((int)hs, 1, 64);
                if (!(lr & 1))
                    gout[(m_g * G3 + cg) >> 1] = (u32)hs | (((u32)(unsigned short)other) << 16);
            }
        }
    }
}

// Persistent recurrence: 64 blocks (2 dirs x 32 h-slices of 16 cols), 256 thr.
//
// Round-6/7 protocol: HINT FLAGS (pacing) + TAGGED DATA (correctness).
// R4/R5 evidence: data-polling re-ingests the full 4MB/step of coherent
// traffic EVERY poll round (~2 rounds x ~1-1.3us contended service); R5's
// chunk retries showed round LATENCY, not size, dominates. Fix: consumers
// first spin on a 128-BYTE flag line (one dword/lane over 32 slices) --
// cheap rounds, low MALL pressure -- and do the 16KB/wave tagged bulk
// ingest ONCE when flags say ready.
// Unlike round-0's flag design, producers NEVER wait: data stores then
// flag store, all fire-and-forget with no vmcnt ack between. If a flag
// overtakes its data (fabric reorder), the consumer's TAG CHECK fails and
// the bulk read retries -- rare, and correctness never rests on ordering.
//
// Tags (unchanged): GRU => |h|<1<2 => bit14 of every published bf16 is 0.
// tag(d)=(d>>1)&1 for generation d in phase buffer d&1; stale same-phase
// data (tag(d-2)!=tag(d)) and cold 0xFF data always mismatch; torn mixes
// caught per-u32. Tag bits STRIPPED (AND 0xBFFFBFFF) before MFMAs (bit14 =
// x2^128). W stays register-resident (48 x bf16x8, R4). Deadlock-free:
// flags are set unconditionally after each publish; induction from the
// pre-loop publish(0)/flag(e+1). ABA-free: producer P publishes gen d+2
// only after P consumed gen d+1 (flag gate over all blocks), and each block
// raises its d+1 flag only after its gen-d bulk read VALIDATED (vmcnt(0)
// precedes the flag store in program order).
__global__ __launch_bounds__(256, 1)
void gru_rec(const bf16* __restrict__ gi,
             const float* __restrict__ whh_f, const float* __restrict__ whh_b,
             const float* __restrict__ bih_f, const float* __restrict__ bhh_f,
             const float* __restrict__ bih_b, const float* __restrict__ bhh_b,
             const float* __restrict__ h0,
             u32* hbuf, u32* flags,
             void* out, float* hn_out, int layer, int out_f32, u32 epoch)
{
    __shared__ bf16 wS[48*512];   // XOR-swizzled: chunk c stored at c^(row&7)
    const int tid = threadIdx.x;
    const int dir = blockIdx.x & 1;
    const int slice = blockIdx.x >> 1;       // 0..31
    const int wave = tid >> 6, lane = tid & 63;
    const int q = lane >> 4, lr = lane & 15;

    const float* whh = dir ? whh_b : whh_f;
    const float* bih = dir ? bih_b : bih_f;
    const float* bhh = dir ? bhh_b : bhh_f;

    // stage W_hh slice -> LDS bf16, 16B chunks, XOR bank swizzle
    for (int idx = tid; idx < 48*64; idx += 256) {
        int row = idx >> 6, c = idx & 63;
        int g = row >> 4, cc = row & 15;
        const float* src = whh + (size_t)(g*HH + slice*16 + cc)*HH + c*8;
        bf16x8 v;
        #pragma unroll
        for (int j = 0; j < 8; ++j) v[j] = (bf16)src[j];
        *(bf16x8*)(wS + row*512 + ((c ^ (row & 7)) << 3)) = v;
    }
    __syncthreads();

    const int sw = lr & 7;

    // ---- hoist W fragments LDS -> registers, ONCE (48 x bf16x8 = 192 VGPR).
    bf16x8 wf[3][16];
    #pragma unroll
    for (int g = 0; g < 3; ++g)
        #pragma unroll
        for (int KK = 0; KK < 16; ++KK)
            wf[g][KK] = *(const bf16x8*)(wS + (g*16 + lr)*512 + (((KK*4 + q) ^ sw) << 3));

    const int col = slice*16 + lr;
    const float bi0 = bih[col], bi1 = bih[HH+col], bi2 = bih[2*HH+col];
    const float bh0 = bhh[col], bh1 = bhh[HH+col], bh2 = bhh[2*HH+col];
    const int mrow = wave*16 + q*4;

    // flag addresses: consumer wave w needs rows [16w,16w+16) => published by
    // producer-wave w of every slice => polls flags[dir][w][0..31] (one line).
    u32* const myfl  = flags + (dir*4 + wave)*32 + slice;        // we write
    const u32* const plfl = flags + (dir*4 + wave)*32 + (lane & 31); // we poll

    float hprev[4];
    #pragma unroll
    for (int i = 0; i < 4; ++i)
        hprev[i] = h0[((2*layer + dir)*BB + mrow + i)*HH + col];

    // publish hv[] into phase buffer ph with tag pattern pat (fire-and-forget)
    auto publish = [&](int ph, u32 pat, const float* hv) {
        u32* hb = hbuf + (((ph << 1) | dir) * 64) * 256;
        #pragma unroll
        for (int i = 0; i < 4; ++i) {
            unsigned short hs = __builtin_bit_cast(unsigned short, (bf16)hv[i]);
            int other = __shfl_xor((int)hs, 1, 64);
            if (!(lr & 1)) {
                u32 u = ((u32)hs | (((u32)(unsigned short)other) << 16)) | pat;
                __hip_atomic_store(hb + (mrow + i)*256 + (col >> 1), u,
                                   __ATOMIC_RELAXED, AGENT);
            }
        }
    };

    // initial h publish: gen d=0, phase 0, tag 0; then advisory flag (no ack!)
    publish(0, 0u, hprev);
    if (lane == 0)
        __hip_atomic_store(myfl, epoch + 1u, __ATOMIC_RELAXED, AGENT);

    const bf16* gbase = gi + (long)dir * TB * G3;
    bf16 gp[3][4];
    {
        int t0 = dir ? (TT-1) : 0;
        #pragma unroll
        for (int g = 0; g < 3; ++g)
            #pragma unroll
            for (int i = 0; i < 4; ++i)
                gp[g][i] = gbase[(long)(t0*BB + mrow + i)*G3 + g*HH + col];
    }

    for (int s = 0; s < TT; ++s) {
        const int t = dir ? (TT-1-s) : s;
        const u32 pat = (s & 2) ? 0x40004000u : 0u;   // tag(d=s) = (s>>1)&1
        const u32* hr = hbuf + ((((s & 1) << 1) | dir)*64 + wave*16 + lr)*256 + q*4;

        // ---- cheap flag gate: 128B line per round (advisory; tags verify)
        {
            const u32 tgt = epoch + 1u + (u32)s;
            for (;;) {
                u32 v = __hip_atomic_load(plfl, __ATOMIC_RELAXED, AGENT);
                if (__all((int)(v >= tgt))) break;
            }
        }

        // ---- single tagged bulk ingest; whole-retry only if a flag raced data
        u32x4 a0,a1,a2,a3,a4,a5,a6,a7,a8,a9,a10,a11,a12,a13,a14,a15;
        for (;;) {
            asm volatile(
                "global_load_dwordx4 %0, %16, off sc0 sc1\n\t"
                "global_load_dwordx4 %1, %16, off offset:64 sc0 sc1\n\t"
                "global_load_dwordx4 %2, %16, off offset:128 sc0 sc1\n\t"
                "global_load_dwordx4 %3, %16, off offset:192 sc0 sc1\n\t"
                "global_load_dwordx4 %4, %16, off offset:256 sc0 sc1\n\t"
                "global_load_dwordx4 %5, %16, off offset:320 sc0 sc1\n\t"
                "global_load_dwordx4 %6, %16, off offset:384 sc0 sc1\n\t"
                "global_load_dwordx4 %7, %16, off offset:448 sc0 sc1\n\t"
                "global_load_dwordx4 %8, %16, off offset:512 sc0 sc1\n\t"
                "global_load_dwordx4 %9, %16, off offset:576 sc0 sc1\n\t"
                "global_load_dwordx4 %10, %16, off offset:640 sc0 sc1\n\t"
                "global_load_dwordx4 %11, %16, off offset:704 sc0 sc1\n\t"
                "global_load_dwordx4 %12, %16, off offset:768 sc0 sc1\n\t"
                "global_load_dwordx4 %13, %16, off offset:832 sc0 sc1\n\t"
                "global_load_dwordx4 %14, %16, off offset:896 sc0 sc1\n\t"
                "global_load_dwordx4 %15, %16, off offset:960 sc0 sc1\n\t"
                "s_waitcnt vmcnt(0)"
                : "=&v"(a0),"=&v"(a1),"=&v"(a2),"=&v"(a3),
                  "=&v"(a4),"=&v"(a5),"=&v"(a6),"=&v"(a7),
                  "=&v"(a8),"=&v"(a9),"=&v"(a10),"=&v"(a11),
                  "=&v"(a12),"=&v"(a13),"=&v"(a14),"=&v"(a15)
                : "v"(hr)
                : "memory");
            __builtin_amdgcn_sched_barrier(0);
#define ORV(v)  (v[0] | v[1] | v[2] | v[3])
#define ANDV(v) (v[0] & v[1] & v[2] & v[3])
            bool ok;
            if (pat) {
                u32 g = ANDV(a0) & ANDV(a1) & ANDV(a2)  & ANDV(a3)
                      & ANDV(a4) & ANDV(a5) & ANDV(a6)  & ANDV(a7)
                      & ANDV(a8) & ANDV(a9) & ANDV(a10) & ANDV(a11)
                      & ANDV(a12)& ANDV(a13)& ANDV(a14) & ANDV(a15);
                ok = (g & 0x40004000u) == 0x40004000u;
            } else {
                u32 b = ORV(a0) | ORV(a1) | ORV(a2)  | ORV(a3)
                      | ORV(a4) | ORV(a5) | ORV(a6)  | ORV(a7)
                      | ORV(a8) | ORV(a9) | ORV(a10) | ORV(a11)
                      | ORV(a12)| ORV(a13)| ORV(a14) | ORV(a15);
                ok = (b & 0x40004000u) == 0u;
            }
#undef ORV
#undef ANDV
            if (__all((int)ok)) break;
        }
        // ---- strip tag bits (bit14 == x2^128 -- must NOT reach the MFMAs)
        if (pat) {
            const u32 SM = 0xBFFFBFFFu;
            auto strip = [&](u32x4& v) {
                v[0] &= SM; v[1] &= SM; v[2] &= SM; v[3] &= SM;
            };
            strip(a0);  strip(a1);  strip(a2);  strip(a3);
            strip(a4);  strip(a5);  strip(a6);  strip(a7);
            strip(a8);  strip(a9);  strip(a10); strip(a11);
            strip(a12); strip(a13); strip(a14); strip(a15);
        }
        // ---- 48 MFMAs, register-only (gh = h @ W_slice^T)
        f32x4 acc0 = {0,0,0,0}, acc1 = {0,0,0,0}, acc2 = {0,0,0,0};
#define KSTEP(KK, AU) { \
            bf16x8 av = __builtin_bit_cast(bf16x8, AU); \
            acc0 = __builtin_amdgcn_mfma_f32_16x16x32_bf16(av, wf[0][KK], acc0, 0,0,0); \
            acc1 = __builtin_amdgcn_mfma_f32_16x16x32_bf16(av, wf[1][KK], acc1, 0,0,0); \
            acc2 = __builtin_amdgcn_mfma_f32_16x16x32_bf16(av, wf[2][KK], acc2, 0,0,0); }
        KSTEP(0,a0)  KSTEP(1,a1)  KSTEP(2,a2)  KSTEP(3,a3)
        KSTEP(4,a4)  KSTEP(5,a5)  KSTEP(6,a6)  KSTEP(7,a7)
        KSTEP(8,a8)  KSTEP(9,a9)  KSTEP(10,a10) KSTEP(11,a11)
        KSTEP(12,a12) KSTEP(13,a13) KSTEP(14,a14) KSTEP(15,a15)
#undef KSTEP
        // ---- fused gates (fp32)
        float hnew[4];
        #pragma unroll
        for (int i = 0; i < 4; ++i) {
            float r = sigm((float)gp[0][i] + bi0 + acc0[i] + bh0);
            float z = sigm((float)gp[1][i] + bi1 + acc1[i] + bh1);
            float n = tanh_f((float)gp[2][i] + bi2 + r * (acc2[i] + bh2));
            float h = (1.0f - z) * n + z * hprev[i];
            hprev[i] = h;
            hnew[i] = h;
        }
        // ---- publish h_new + advisory flag (both fire-and-forget, data first)
        if (s < TT-1) {
            u32 npat = ((s+1) & 2) ? 0x40004000u : 0u;  // tag(d=s+1)
            publish((s+1) & 1, npat, hnew);
            if (lane == 0)
                __hip_atomic_store(myfl, epoch + 2u + (u32)s,
                                   __ATOMIC_RELAXED, AGENT);
        }
        // ---- write y[t] (overlaps next step's flag-poll window)
        if (out_f32) {
            float* yo = (float*)out;
            #pragma unroll
            for (int i = 0; i < 4; ++i)
                yo[(long)(t*BB + mrow + i)*1024 + dir*HH + col] = hnew[i];
        } else {
            bf16* yo = (bf16*)out;
            #pragma unroll
            for (int i = 0; i < 4; ++i)
                yo[(long)(t*BB + mrow + i)*1024 + dir*HH + col] = (bf16)hnew[i];
        }
        if (s == TT-1) {
            #pragma unroll
            for (int i = 0; i < 4; ++i)
                hn_out[((2*layer + dir)*BB + mrow + i)*HH + col] = hnew[i];
            break;
        }
        // ---- prefetch next gi (overlaps next step's flag-poll window)
        int tn = dir ? (TT-2-s) : (s+1);
        #pragma unroll
        for (int g = 0; g < 3; ++g)
            #pragma unroll
            for (int i = 0; i < 4; ++i)
                gp[g][i] = gbase[(long)(tn*BB + mrow + i)*G3 + g*HH + col];
    }
}

// ============================ launch ============================
extern "C" void kernel_launch(void* const* d_in, const int* in_sizes, int n_in,
                              void* d_out, int out_size, void* d_ws, size_t ws_size,
                              hipStream_t stream)
{
    const float* x     = (const float*)d_in[0];
    const float* h0    = (const float*)d_in[1];
    const float* wih0f = (const float*)d_in[2];
    const float* whh0f = (const float*)d_in[3];
    const float* bih0f = (const float*)d_in[4];
    const float* bhh0f = (const float*)d_in[5];
    const float* wih0b = (const float*)d_in[6];
    const float* whh0b = (const float*)d_in[7];
    const float* bih0b = (const float*)d_in[8];
    const float* bhh0b = (const float*)d_in[9];
    const float* wih1f = (const float*)d_in[10];
    const float* whh1f = (const float*)d_in[11];
    const float* bih1f = (const float*)d_in[12];
    const float* bhh1f = (const float*)d_in[13];
    const float* wih1b = (const float*)d_in[14];
    const float* whh1b = (const float*)d_in[15];
    const float* bih1b = (const float*)d_in[16];
    const float* bhh1b = (const float*)d_in[17];

    if (ws_size < (size_t)WS_NEED) {
        sentinel<<<1, 1, 0, stream>>>((float*)d_out);
        return;
    }
    char* ws = (char*)d_ws;
    bf16* gi    = (bf16*)(ws + GI_OFF);
    bf16* l0out = (bf16*)(ws + L0_OFF);
    bf16* xb    = (bf16*)(ws + XB_OFF);
    bf16* w0    = (bf16*)(ws + W0_OFF);
    bf16* w1    = (bf16*)(ws + W1_OFF);
    u32*  hbuf  = (u32*)(ws + HB_OFF);
    u32*  flags = (u32*)(ws + FL_OFF);
    float* hn   = (float*)d_out + (long)TB * 1024;

    // hbuf 0xFF: cold/stale tags mismatch the first expected generations.
    // Between layers no re-memset needed: layer 0 ends with gens 510/511
    // (both tag 1) resident; layer 1 starts expecting tag 0.
    // flags 0: layer epochs (0, 4096) keep targets strictly increasing.
    hipMemsetAsync(hbuf, 0xFF, HB_BYTES, stream);
    hipMemsetAsync(flags, 0, FL_BYTES, stream);

    // bf16 packing
    cvt_f32_bf16<<<2048, 256, 0, stream>>>(x, xb, (long)TB * 512);
    cvt_f32_bf16<<<256, 256, 0, stream>>>(wih0f, w0,             (long)G3 * 512);
    cvt_f32_bf16<<<256, 256, 0, stream>>>(wih0b, w0 + G3*512L,   (long)G3 * 512);
    cvt_f32_bf16<<<256, 256, 0, stream>>>(wih1f, w1,             (long)G3 * 1024);
    cvt_f32_bf16<<<256, 256, 0, stream>>>(wih1b, w1 + G3*1024L,  (long)G3 * 1024);

    // layer 0
    gemm_gi<<<dim3(256 * 24), 256, 0, stream>>>(xb, w0, gi, 512);
    gru_rec<<<64, 256, 0, stream>>>(gi, whh0f, whh0b, bih0f, bhh0f, bih0b, bhh0b,
                                    h0, hbuf, flags, (void*)l0out, hn, 0, 0, 0u);
    // layer 1
    gemm_gi<<<dim3(256 * 24), 256, 0, stream>>>(l0out, w1, gi, 1024);
    gru_rec<<<64, 256, 0, stream>>>(gi, whh1f, whh1b, bih1f, bhh1f, bih1b, bhh1b,
                                    h0, hbuf, flags, d_out, hn, 1, 1, 4096u);
}

// Round 8
// 3224.987 us; speedup vs baseline: 2.2984x; 1.3675x over previous
//
#include <hip/hip_runtime.h>
#include <hip/hip_bf16.h>

typedef __bf16 bf16;
typedef bf16 bf16x8 __attribute__((ext_vector_type(8)));
typedef float f32x4 __attribute__((ext_vector_type(4)));
typedef unsigned int u32;
typedef u32 u32x4 __attribute__((ext_vector_type(4)));

#define AGENT __HIP_MEMORY_SCOPE_AGENT

// ---- problem sizes ----
#define TT 512
#define BB 64
#define HH 512
#define TB (TT*BB)      // 32768 rows
#define G3 (3*HH)       // 1536 gates per dir

// ---- workspace layout (bytes) ----
#define GI_OFF   0L
#define GI_BYTES (2L*TB*G3*2)          // bf16 gi, both dirs
#define L0_OFF   (GI_OFF + GI_BYTES)
#define L0_BYTES (1L*TB*1024*2)        // bf16 layer-0 output
#define XB_OFF   (L0_OFF + L0_BYTES)
#define XB_BYTES (1L*TB*512*2)         // bf16 x
#define W0_OFF   (XB_OFF + XB_BYTES)
#define W0_BYTES (3072L*512*2)         // packed w_ih L0 (f then b)
#define W1_OFF   (W0_OFF + W0_BYTES)
#define W1_BYTES (3072L*1024*2)        // packed w_ih L1
#define HB_OFF   (W1_OFF + W1_BYTES)
#define HB_BYTES (2L*2*64*256*4)       // h exchange: [phase][dir][64][256] u32 (bf16 pairs)
#define FL_OFF   (HB_OFF + HB_BYTES)
#define FL_BYTES 1024                  // flags[dir][r][c'][w'] u32 (256 used)
#define WS_NEED  (FL_OFF + FL_BYTES)

// ============================ helpers ============================
__device__ __forceinline__ float sigm(float x) {
    return __builtin_amdgcn_rcpf(1.0f + __expf(-x));
}
__device__ __forceinline__ float tanh_f(float x) {
    return 1.0f - 2.0f * __builtin_amdgcn_rcpf(1.0f + __expf(2.0f * x));
}

// ============================ kernels ============================
__global__ void sentinel(float* o) { o[0] = 1.0e9f; }  // ws too small marker

__global__ void cvt_f32_bf16(const float* __restrict__ s, bf16* __restrict__ d, long n) {
    long i = (long)blockIdx.x * blockDim.x + threadIdx.x;
    long st = (long)gridDim.x * blockDim.x;
    for (; i < n; i += st) d[i] = (bf16)s[i];
}

// C[m, n] = sum_k A[m,k] * Bw[n,k]; A row-major [32768,K] bf16, Bw [3072,K] bf16.
// Output written as bf16 into gi[dir][m][col], dir = n>=1536.
__global__ __launch_bounds__(256, 2)
void gemm_gi(const bf16* __restrict__ A, const bf16* __restrict__ Bw,
             bf16* __restrict__ gi, int K)
{
    __shared__ bf16 aS[128*72];
    __shared__ bf16 bS[128*72];
    const int tid = threadIdx.x;
    const int mt = blockIdx.x & 255;
    const int nt = blockIdx.x >> 8;
    const long m0 = (long)mt * 128;
    const int n0 = nt * 128;
    const int wave = tid >> 6, lane = tid & 63;
    const int q = lane >> 4, lr = lane & 15;
    const int wm = wave & 1, wn = wave >> 1;
    f32x4 acc[4][4] = {};

    for (int kb = 0; kb < K; kb += 64) {
        __syncthreads();
        #pragma unroll
        for (int p = 0; p < 4; ++p) {
            int idx = tid + p * 256;
            int row = idx >> 3, qd = idx & 7;
            *(uint4*)(aS + row*72 + qd*8) = *(const uint4*)(A + (m0+row)*K + kb + qd*8);
            *(uint4*)(bS + row*72 + qd*8) = *(const uint4*)(Bw + (long)(n0+row)*K + kb + qd*8);
        }
        __syncthreads();
        #pragma unroll
        for (int kk = 0; kk < 2; ++kk) {
            bf16x8 af[4], bfr[4];
            #pragma unroll
            for (int sm = 0; sm < 4; ++sm)
                af[sm] = *(const bf16x8*)(aS + (wm*64 + sm*16 + lr)*72 + kk*32 + q*8);
            #pragma unroll
            for (int sn = 0; sn < 4; ++sn)
                bfr[sn] = *(const bf16x8*)(bS + (wn*64 + sn*16 + lr)*72 + kk*32 + q*8);
            #pragma unroll
            for (int sm = 0; sm < 4; ++sm)
                #pragma unroll
                for (int sn = 0; sn < 4; ++sn)
                    acc[sm][sn] = __builtin_amdgcn_mfma_f32_16x16x32_bf16(
                        af[sm], bfr[sn], acc[sm][sn], 0, 0, 0);
        }
    }
    #pragma unroll
    for (int sm = 0; sm < 4; ++sm) {
        #pragma unroll
        for (int sn = 0; sn < 4; ++sn) {
            int n_g = n0 + wn*64 + sn*16 + lr;
            int d = (n_g >= G3) ? 1 : 0;
            int cg = n_g - d * G3;
            u32* gout = (u32*)(gi + (long)d * TB * G3);
            #pragma unroll
            for (int i = 0; i < 4; ++i) {
                long m_g = m0 + wm*64 + sm*16 + q*4 + i;
                unsigned short hs = __builtin_bit_cast(unsigned short, (bf16)acc[sm][sn][i]);
                int other = __shfl_xor((int)hs, 1, 64);
                if (!(lr & 1))
                    gout[(m_g * G3 + cg) >> 1] = (u32)hs | (((u32)(unsigned short)other) << 16);
            }
        }
    }
}

// Persistent recurrence: 64 blocks = 2 dirs x 4 row-groups (16 rows) x 8
// col-slices (64 cols), 256 thr.
//
// Round-8 change: 2-D (row x col) DECOMPOSITION + LDS-SHARED INGEST.
// The GRU recurrence is row-independent, so block (r,c) needs h only for
// ITS 16 rows (all K): 16KB/block instead of 64KB -> total exchange traffic
// 1MB/step (was 4MB), and the dependency graph decomposes into 8-block
// cliques (fixed r,dir) -> fan-in 8 (was 32). The block's 4 waves share one
// LDS copy: cooperative coalesced load (1KB/row contiguous per wave-instr),
// tag-validate, swizzled ds_write, syncthreads, ds_read A-fragments.
// W stays register-resident per wave (48 x bf16x8 for its 16 cols), staged
// via 4 sequential one-time LDS passes. Block->(dir,r,c) mapping groups
// each clique on one XCD under the b%8 heuristic (perf-neutral if wrong).
//
// Protocol (R7, unchanged): HINT FLAGS (pacing) + TAGGED DATA (correctness).
// GRU => |h|<1<2 => bit14 of each published bf16 is 0; tag(d)=(d>>1)&1 in
// phase buffer d&1. Producers fire-and-forget (data stores then flag store,
// no ack); consumers gate on a flag line then do ONE tagged bulk ingest;
// tag mismatch (fabric reorder, rare) retries the load. Tag bits stripped
// (AND 0xBFFFBFFF) before use (bit14 = x2^128).
// LDS reuse safety: wave X ds_writes hS for step s only after the flag gate
// for s passed, which includes its OWN block's waves' flags for gen s; a
// wave sets that flag only after publish(s), which data-depends on its
// MFMA reads of hS(s-1). So no wave can overwrite hS while another reads.
// ABA: flag(d+1) is stored after the gen-d ingest VALIDATED (vmcnt(0) in
// program order), so gate(d+1) implies all clique readers of gen d done.
__global__ __launch_bounds__(256, 1)
void gru_rec(const bf16* __restrict__ gi,
             const float* __restrict__ whh_f, const float* __restrict__ whh_b,
             const float* __restrict__ bih_f, const float* __restrict__ bhh_f,
             const float* __restrict__ bih_b, const float* __restrict__ bhh_b,
             const float* __restrict__ h0,
             u32* hbuf, u32* flags,
             void* out, float* hn_out, int layer, int out_f32, u32 epoch)
{
    __shared__ __align__(16) char smem[48*1024];   // W staging (48KB) / h tile (16KB)
    bf16* wSt = (bf16*)smem;
    u32*  hS  = (u32*)smem;
    const int tid = threadIdx.x;
    const int b   = blockIdx.x;
    const int dir = b & 1;               // clique (dir,r) = fixed b&7 -> one XCD
    const int r   = (b >> 1) & 3;        // row-group: rows 16r..16r+15
    const int c   = b >> 3;              // col-slice: cols 64c..64c+63
    const int wave = tid >> 6, lane = tid & 63;
    const int q = lane >> 4, lr = lane & 15;

    const float* whh = dir ? whh_b : whh_f;
    const float* bih = dir ? bih_b : bih_f;
    const float* bhh = dir ? bhh_b : bhh_f;

    const int col  = c*64 + wave*16 + lr;    // this thread's output column
    const int mrow = 16*r + q*4;             // this thread's first output row

    // flag line for clique (dir,r): 32 entries = [c' 0..7][w' 0..3]
    u32* const myfl = flags + (dir*4 + r)*32 + c*4 + wave;
    const u32* const plfl = flags + (dir*4 + r)*32 + (lane & 31);

    float hprev[4];
    #pragma unroll
    for (int i = 0; i < 4; ++i)
        hprev[i] = h0[((2*layer + dir)*BB + mrow + i)*HH + col];

    // publish hv[] into phase buffer ph with tag pattern pat (fire-and-forget)
    auto publish = [&](int ph, u32 pat, const float* hv) {
        u32* hb = hbuf + (((ph << 1) | dir) * 64) * 256;
        #pragma unroll
        for (int i = 0; i < 4; ++i) {
            unsigned short hs = __builtin_bit_cast(unsigned short, (bf16)hv[i]);
            int other = __shfl_xor((int)hs, 1, 64);
            if (!(lr & 1)) {
                u32 u = ((u32)hs | (((u32)(unsigned short)other) << 16)) | pat;
                __hip_atomic_store(hb + (mrow + i)*256 + (col >> 1), u,
                                   __ATOMIC_RELAXED, AGENT);
            }
        }
    };

    // initial publish FIRST (on the wire before the long W staging), gen 0
    publish(0, 0u, hprev);
    if (lane == 0)
        __hip_atomic_store(myfl, epoch + 1u, __ATOMIC_RELAXED, AGENT);

    // ---- W staging: 4 sequential passes; pass w stages wave-w's 16 cols
    //      (48 W-rows x 512 k) into LDS, wave w hoists to registers.
    bf16x8 wf[3][16];
    for (int w = 0; w < 4; ++w) {
        for (int idx = tid; idx < 48*64; idx += 256) {
            int row = idx >> 6, ch = idx & 63;
            int g = row >> 4, cc = row & 15;
            const float* src = whh + (size_t)(g*HH + c*64 + w*16 + cc)*HH + ch*8;
            bf16x8 v;
            #pragma unroll
            for (int j = 0; j < 8; ++j) v[j] = (bf16)src[j];
            *(bf16x8*)(wSt + row*512 + ((ch ^ (row & 7)) << 3)) = v;
        }
        __syncthreads();
        if (wave == w) {
            #pragma unroll
            for (int g = 0; g < 3; ++g)
                #pragma unroll
                for (int KK = 0; KK < 16; ++KK)
                    wf[g][KK] = *(const bf16x8*)(wSt + (g*16 + lr)*512 +
                                                 (((KK*4 + q) ^ (lr & 7)) << 3));
        }
        __syncthreads();
    }

    const float bi0 = bih[col], bi1 = bih[HH+col], bi2 = bih[2*HH+col];
    const float bh0 = bhh[col], bh1 = bhh[HH+col], bh2 = bhh[2*HH+col];

    const bf16* gbase = gi + (long)dir * TB * G3;
    bf16 gp[3][4];
    {
        int t0 = dir ? (TT-1) : 0;
        #pragma unroll
        for (int g = 0; g < 3; ++g)
            #pragma unroll
            for (int i = 0; i < 4; ++i)
                gp[g][i] = gbase[(long)(t0*BB + mrow + i)*G3 + g*HH + col];
    }

    for (int s = 0; s < TT; ++s) {
        const int t = dir ? (TT-1-s) : s;
        const u32 pat = (s & 2) ? 0x40004000u : 0u;   // tag(d=s) = (s>>1)&1

        // ---- cheap flag gate: one 128B line (8 producer blocks x 4 waves)
        {
            const u32 tgt = epoch + 1u + (u32)s;
            for (;;) {
                u32 v = __hip_atomic_load(plfl, __ATOMIC_RELAXED, AGENT);
                if (__all((int)(v >= tgt))) break;
            }
        }

        // ---- cooperative tagged ingest: 16KB/block (rows 16r..+15, all K).
        // Wave w, instr j: row 16r+4w+j, lanes cover 1KB contiguous.
        const u32* hp = hbuf + ((((s & 1) << 1) | dir)*64 + 16*r + 4*wave)*256
                      + lane*4;
        u32x4 d0, d1, d2, d3;
        for (;;) {
            asm volatile(
                "global_load_dwordx4 %0, %4, off sc0 sc1\n\t"
                "global_load_dwordx4 %1, %4, off offset:1024 sc0 sc1\n\t"
                "global_load_dwordx4 %2, %4, off offset:2048 sc0 sc1\n\t"
                "global_load_dwordx4 %3, %4, off offset:3072 sc0 sc1\n\t"
                "s_waitcnt vmcnt(0)"
                : "=&v"(d0), "=&v"(d1), "=&v"(d2), "=&v"(d3)
                : "v"(hp)
                : "memory");
            __builtin_amdgcn_sched_barrier(0);
            bool ok;
            if (pat) {
                u32 g = (d0[0]&d0[1]&d0[2]&d0[3]) & (d1[0]&d1[1]&d1[2]&d1[3])
                      & (d2[0]&d2[1]&d2[2]&d2[3]) & (d3[0]&d3[1]&d3[2]&d3[3]);
                ok = (g & 0x40004000u) == 0x40004000u;
            } else {
                u32 o = (d0[0]|d0[1]|d0[2]|d0[3]) | (d1[0]|d1[1]|d1[2]|d1[3])
                      | (d2[0]|d2[1]|d2[2]|d2[3]) | (d3[0]|d3[1]|d3[2]|d3[3]);
                ok = (o & 0x40004000u) == 0u;
            }
            if (__all((int)ok)) break;
        }
        // strip tag bits (bit14 = x2^128 -- must not reach the MFMAs)
        if (pat) {
            const u32 SM = 0xBFFFBFFFu;
            #pragma unroll
            for (int j = 0; j < 4; ++j) { d0[j] &= SM; d1[j] &= SM; d2[j] &= SM; d3[j] &= SM; }
        }
        // ds_write into swizzled h tile: logical u32 col X at X ^ ((row&15)<<2)
        {
            #pragma unroll
            for (int j = 0; j < 4; ++j) {
                int row = 4*wave + j;
                u32x4 v = (j == 0) ? d0 : (j == 1) ? d1 : (j == 2) ? d2 : d3;
                *(u32x4*)&hS[row*256 + ((lane*4) ^ ((row & 15) << 2))] = v;
            }
        }
        __syncthreads();

        // ---- 48 MFMAs: A (16 rows x K) from shared LDS tile, B (W) from regs
        f32x4 acc0 = {0,0,0,0}, acc1 = {0,0,0,0}, acc2 = {0,0,0,0};
        #pragma unroll
        for (int KK = 0; KK < 16; ++KK) {
            bf16x8 av = *(const bf16x8*)&hS[lr*256 + ((KK*16 + q*4) ^ ((lr & 15) << 2))];
            acc0 = __builtin_amdgcn_mfma_f32_16x16x32_bf16(av, wf[0][KK], acc0, 0,0,0);
            acc1 = __builtin_amdgcn_mfma_f32_16x16x32_bf16(av, wf[1][KK], acc1, 0,0,0);
            acc2 = __builtin_amdgcn_mfma_f32_16x16x32_bf16(av, wf[2][KK], acc2, 0,0,0);
        }
        // ---- fused gates (fp32)
        float hnew[4];
        #pragma unroll
        for (int i = 0; i < 4; ++i) {
            float rr = sigm((float)gp[0][i] + bi0 + acc0[i] + bh0);
            float z  = sigm((float)gp[1][i] + bi1 + acc1[i] + bh1);
            float n  = tanh_f((float)gp[2][i] + bi2 + rr * (acc2[i] + bh2));
            float h  = (1.0f - z) * n + z * hprev[i];
            hprev[i] = h;
            hnew[i]  = h;
        }
        // ---- publish h_new + advisory flag (fire-and-forget, data first)
        if (s < TT-1) {
            u32 npat = ((s+1) & 2) ? 0x40004000u : 0u;
            publish((s+1) & 1, npat, hnew);
            if (lane == 0)
                __hip_atomic_store(myfl, epoch + 2u + (u32)s,
                                   __ATOMIC_RELAXED, AGENT);
        }
        // ---- write y[t] (overlaps next step's flag-poll window)
        if (out_f32) {
            float* yo = (float*)out;
            #pragma unroll
            for (int i = 0; i < 4; ++i)
                yo[(long)(t*BB + mrow + i)*1024 + dir*HH + col] = hnew[i];
        } else {
            bf16* yo = (bf16*)out;
            #pragma unroll
            for (int i = 0; i < 4; ++i)
                yo[(long)(t*BB + mrow + i)*1024 + dir*HH + col] = (bf16)hnew[i];
        }
        if (s == TT-1) {
            #pragma unroll
            for (int i = 0; i < 4; ++i)
                hn_out[((2*layer + dir)*BB + mrow + i)*HH + col] = hnew[i];
            break;
        }
        // ---- prefetch next gi (overlaps next step's flag-poll window)
        int tn = dir ? (TT-2-s) : (s+1);
        #pragma unroll
        for (int g = 0; g < 3; ++g)
            #pragma unroll
            for (int i = 0; i < 4; ++i)
                gp[g][i] = gbase[(long)(tn*BB + mrow + i)*G3 + g*HH + col];
    }
}

// ============================ launch ============================
extern "C" void kernel_launch(void* const* d_in, const int* in_sizes, int n_in,
                              void* d_out, int out_size, void* d_ws, size_t ws_size,
                              hipStream_t stream)
{
    const float* x     = (const float*)d_in[0];
    const float* h0    = (const float*)d_in[1];
    const float* wih0f = (const float*)d_in[2];
    const float* whh0f = (const float*)d_in[3];
    const float* bih0f = (const float*)d_in[4];
    const float* bhh0f = (const float*)d_in[5];
    const float* wih0b = (const float*)d_in[6];
    const float* whh0b = (const float*)d_in[7];
    const float* bih0b = (const float*)d_in[8];
    const float* bhh0b = (const float*)d_in[9];
    const float* wih1f = (const float*)d_in[10];
    const float* whh1f = (const float*)d_in[11];
    const float* bih1f = (const float*)d_in[12];
    const float* bhh1f = (const float*)d_in[13];
    const float* wih1b = (const float*)d_in[14];
    const float* whh1b = (const float*)d_in[15];
    const float* bih1b = (const float*)d_in[16];
    const float* bhh1b = (const float*)d_in[17];

    if (ws_size < (size_t)WS_NEED) {
        sentinel<<<1, 1, 0, stream>>>((float*)d_out);
        return;
    }
    char* ws = (char*)d_ws;
    bf16* gi    = (bf16*)(ws + GI_OFF);
    bf16* l0out = (bf16*)(ws + L0_OFF);
    bf16* xb    = (bf16*)(ws + XB_OFF);
    bf16* w0    = (bf16*)(ws + W0_OFF);
    bf16* w1    = (bf16*)(ws + W1_OFF);
    u32*  hbuf  = (u32*)(ws + HB_OFF);
    u32*  flags = (u32*)(ws + FL_OFF);
    float* hn   = (float*)d_out + (long)TB * 1024;

    // hbuf 0xFF: cold/stale tags mismatch the first expected generations.
    // Between layers no re-memset needed: layer 0 ends with gens 510/511
    // (both tag 1) resident; layer 1 starts expecting tag 0.
    // flags 0: layer epochs (0, 4096) keep targets strictly increasing.
    hipMemsetAsync(hbuf, 0xFF, HB_BYTES, stream);
    hipMemsetAsync(flags, 0, FL_BYTES, stream);

    // bf16 packing
    cvt_f32_bf16<<<2048, 256, 0, stream>>>(x, xb, (long)TB * 512);
    cvt_f32_bf16<<<256, 256, 0, stream>>>(wih0f, w0,             (long)G3 * 512);
    cvt_f32_bf16<<<256, 256, 0, stream>>>(wih0b, w0 + G3*512L,   (long)G3 * 512);
    cvt_f32_bf16<<<256, 256, 0, stream>>>(wih1f, w1,             (long)G3 * 1024);
    cvt_f32_bf16<<<256, 256, 0, stream>>>(wih1b, w1 + G3*1024L,  (long)G3 * 1024);

    // layer 0
    gemm_gi<<<dim3(256 * 24), 256, 0, stream>>>(xb, w0, gi, 512);
    gru_rec<<<64, 256, 0, stream>>>(gi, whh0f, whh0b, bih0f, bhh0f, bih0b, bhh0b,
                                    h0, hbuf, flags, (void*)l0out, hn, 0, 0, 0u);
    // layer 1
    gemm_gi<<<dim3(256 * 24), 256, 0, stream>>>(l0out, w1, gi, 1024);
    gru_rec<<<64, 256, 0, stream>>>(gi, whh1f, whh1b, bih1f, bhh1f, bih1b, bhh1b,
                                    h0, hbuf, flags, d_out, hn, 1, 1, 4096u);
}